// Round 4
// baseline (62.528 us; speedup 1.0000x reference)
//
#include <hip/hip_runtime.h>

// loss = sum_{b,m,n} | dot(src[b,n,:], tgts[b,m,n,:]) |
// B=64, M=16, N=64, D=1024
//
// v1 structure (one wave per row, grid-stride, full occupancy) + two levers:
//  - unroll-by-2: each wave processes TWO consecutive rows per iteration
//    (16 KiB of loads in flight, two independent FMA/reduce chains)
//  - nontemporal loads on the 256 MiB zero-reuse tgts stream (nt flag),
//    normal (caching) loads for the 16 MiB src (L2/L3-resident, re-read 16x)

typedef __attribute__((ext_vector_type(4))) float f32x4;

__global__ __launch_bounds__(256, 4) void orth_loss_kernel(
    const float* __restrict__ src,
    const float* __restrict__ tgts,
    float* __restrict__ out,
    int total_pairs)   // B*M*N/2 = 32768
{
    const int wave = threadIdx.x >> 6;   // 0..3
    const int lane = threadIdx.x & 63;

    float local = 0.0f;

    for (int p = blockIdx.x * 4 + wave; p < total_pairs; p += gridDim.x * 4) {
        const int r0 = p * 2;            // even row; r0+1 shares (b,m), n+1
        const int n0 = r0 & 63;          // even, so n0+1 <= 63 (no bm cross)
        const int bm = r0 >> 6;
        const int b  = bm >> 4;

        const f32x4* __restrict__ tp0 =
            reinterpret_cast<const f32x4*>(tgts + (size_t)r0 * 1024);
        const f32x4* __restrict__ tp1 =
            reinterpret_cast<const f32x4*>(tgts + (size_t)(r0 + 1) * 1024);
        const f32x4* __restrict__ sp0 =
            reinterpret_cast<const f32x4*>(src + ((size_t)(b * 64 + n0)) * 1024);
        const f32x4* __restrict__ sp1 =
            reinterpret_cast<const f32x4*>(src + ((size_t)(b * 64 + n0 + 1)) * 1024);

        // issue all 16 loads (8 NT tgts + 8 cached src), then two dot chains
        const f32x4 ta0 = __builtin_nontemporal_load(tp0 + lane);
        const f32x4 ta1 = __builtin_nontemporal_load(tp0 + lane + 64);
        const f32x4 ta2 = __builtin_nontemporal_load(tp0 + lane + 128);
        const f32x4 ta3 = __builtin_nontemporal_load(tp0 + lane + 192);
        const f32x4 tb0 = __builtin_nontemporal_load(tp1 + lane);
        const f32x4 tb1 = __builtin_nontemporal_load(tp1 + lane + 64);
        const f32x4 tb2 = __builtin_nontemporal_load(tp1 + lane + 128);
        const f32x4 tb3 = __builtin_nontemporal_load(tp1 + lane + 192);
        const f32x4 sa0 = sp0[lane];
        const f32x4 sa1 = sp0[lane + 64];
        const f32x4 sa2 = sp0[lane + 128];
        const f32x4 sa3 = sp0[lane + 192];
        const f32x4 sb0 = sp1[lane];
        const f32x4 sb1 = sp1[lane + 64];
        const f32x4 sb2 = sp1[lane + 128];
        const f32x4 sb3 = sp1[lane + 192];

        float dotA = 0.0f, dotB = 0.0f;
        dotA = fmaf(ta0.x, sa0.x, dotA); dotB = fmaf(tb0.x, sb0.x, dotB);
        dotA = fmaf(ta0.y, sa0.y, dotA); dotB = fmaf(tb0.y, sb0.y, dotB);
        dotA = fmaf(ta0.z, sa0.z, dotA); dotB = fmaf(tb0.z, sb0.z, dotB);
        dotA = fmaf(ta0.w, sa0.w, dotA); dotB = fmaf(tb0.w, sb0.w, dotB);
        dotA = fmaf(ta1.x, sa1.x, dotA); dotB = fmaf(tb1.x, sb1.x, dotB);
        dotA = fmaf(ta1.y, sa1.y, dotA); dotB = fmaf(tb1.y, sb1.y, dotB);
        dotA = fmaf(ta1.z, sa1.z, dotA); dotB = fmaf(tb1.z, sb1.z, dotB);
        dotA = fmaf(ta1.w, sa1.w, dotA); dotB = fmaf(tb1.w, sb1.w, dotB);
        dotA = fmaf(ta2.x, sa2.x, dotA); dotB = fmaf(tb2.x, sb2.x, dotB);
        dotA = fmaf(ta2.y, sa2.y, dotA); dotB = fmaf(tb2.y, sb2.y, dotB);
        dotA = fmaf(ta2.z, sa2.z, dotA); dotB = fmaf(tb2.z, sb2.z, dotB);
        dotA = fmaf(ta2.w, sa2.w, dotA); dotB = fmaf(tb2.w, sb2.w, dotB);
        dotA = fmaf(ta3.x, sa3.x, dotA); dotB = fmaf(tb3.x, sb3.x, dotB);
        dotA = fmaf(ta3.y, sa3.y, dotA); dotB = fmaf(tb3.y, sb3.y, dotB);
        dotA = fmaf(ta3.z, sa3.z, dotA); dotB = fmaf(tb3.z, sb3.z, dotB);
        dotA = fmaf(ta3.w, sa3.w, dotA); dotB = fmaf(tb3.w, sb3.w, dotB);

        // two independent 64-lane butterfly reduces (chains interleave)
#pragma unroll
        for (int off = 32; off > 0; off >>= 1) {
            dotA += __shfl_down(dotA, off, 64);
            dotB += __shfl_down(dotB, off, 64);
        }

        if (lane == 0) local += fabsf(dotA) + fabsf(dotB);
    }

    __shared__ float sbuf[4];
    if (lane == 0) sbuf[wave] = local;
    __syncthreads();

    if (threadIdx.x == 0) {
        const float s = sbuf[0] + sbuf[1] + sbuf[2] + sbuf[3];
        atomicAdd(out, s);
    }
}

extern "C" void kernel_launch(void* const* d_in, const int* in_sizes, int n_in,
                              void* d_out, int out_size, void* d_ws, size_t ws_size,
                              hipStream_t stream) {
    const float* src  = (const float*)d_in[0];   // [B, N, D]
    const float* tgts = (const float*)d_in[1];   // [B, M, N, D]
    float* out = (float*)d_out;                  // [1]

    const int total_rows  = in_sizes[1] / 1024;  // B*M*N = 65536
    const int total_pairs = total_rows / 2;      // 32768

    hipMemsetAsync(out, 0, sizeof(float), stream);

    const int blocks = 2048;   // 8 blocks/CU; 4 pair-iterations per wave
    orth_loss_kernel<<<blocks, 256, 0, stream>>>(src, tgts, out, total_pairs);
}

// Round 5
// 50.282 us; speedup vs baseline: 1.2436x; 1.2436x over previous
//
#include <hip/hip_runtime.h>
#include <stdint.h>

// loss = sum_{b,m,n} | dot(src[b,n,:], tgts[b,m,n,:]) |
// B=64, M=16, N=64, D=1024
//
// DMA-streaming structure (T3/T4 style): one wave per (b, n, m-half).
// All data fetched with global_load_lds (program-ordered intrinsics) into a
// per-wave 3-deep LDS ring; hand-counted s_waitcnt vmcnt(8) keeps 2 rows
// (8 KiB/wave) in flight at ALL times -- the vmcnt queue never drains in the
// steady state. src row fetched once via the same path, then kept in regs.
// No memset dispatch, no atomics: block partials -> d_ws, 1-block reduce.

typedef __attribute__((ext_vector_type(4))) float f32x4;
typedef const __attribute__((address_space(1))) void* gvp;
typedef __attribute__((address_space(3))) void* svp;

#define GLDS(gp, lp) \
  __builtin_amdgcn_global_load_lds((gvp)(gp), (svp)(lp), 16, 0, 0)

#define WAITV(n) asm volatile("s_waitcnt vmcnt(" #n ")" ::: "memory")
#define CFENCE() asm volatile("" ::: "memory")

__global__ __launch_bounds__(256) void orth_loss_main(
    const float* __restrict__ src,
    const float* __restrict__ tgts,
    float* __restrict__ partials)
{
    __shared__ float ring[4][3][1024];   // 4 waves x 3 row-buffers x 4 KiB
    __shared__ float srcb[4][1024];      // 4 waves x src row
    __shared__ float sbuf[4];

    const int wave = threadIdx.x >> 6;   // 0..3
    const int lane = threadIdx.x & 63;

    const int w  = blockIdx.x * 4 + wave;   // 0..8191, exact grid
    const int n  = w & 63;                  // N = 64
    const int t  = w >> 6;
    const int mh = t & 1;                   // m-half: rows m = mh*8 + 0..7
    const int b  = t >> 1;

    const float* srow = src + ((size_t)(b * 64 + n)) * 1024 + lane * 4;
    const int    base_row = (b * 16 + mh * 8) * 64 + n;
    const float* trow = tgts + (size_t)base_row * 1024 + lane * 4;
    const size_t mstride = (size_t)64 * 1024;   // floats between m-rows

    // ---- prologue: src (4 ops) + rows 0,1,2 (12 ops) = 16 outstanding ----
#pragma unroll
    for (int k = 0; k < 4; ++k)
        GLDS(srow + k * 256, &srcb[wave][k * 256]);
#pragma unroll
    for (int r = 0; r < 3; ++r) {
#pragma unroll
        for (int k = 0; k < 4; ++k)
            GLDS(trow + r * mstride + k * 256, &ring[wave][r][k * 256]);
    }

    float local = 0.0f;
    f32x4 s0, s1, s2, s3;

    // Steady state: wait vmcnt(8) (oldest row + src done, 2 rows stay in
    // flight), compute from LDS, then reuse the just-consumed buffer for
    // row mi+3. Tail: vmcnt 8 -> 4 -> 0.
#define STEP(MI, DO_ISSUE, WN) do {                                          \
      WAITV(WN);                                                             \
      if ((MI) == 0) {                                                       \
        const f32x4* sb_ = (const f32x4*)&srcb[wave][0];                     \
        s0 = sb_[lane];       s1 = sb_[lane + 64];                           \
        s2 = sb_[lane + 128]; s3 = sb_[lane + 192];                          \
      }                                                                      \
      const f32x4* lb_ = (const f32x4*)&ring[wave][(MI) % 3][0];             \
      const f32x4 t0 = lb_[lane];                                            \
      const f32x4 t1 = lb_[lane + 64];                                       \
      const f32x4 t2 = lb_[lane + 128];                                      \
      const f32x4 t3 = lb_[lane + 192];                                      \
      float dot = 0.0f;                                                      \
      dot = fmaf(t0.x, s0.x, dot); dot = fmaf(t0.y, s0.y, dot);              \
      dot = fmaf(t0.z, s0.z, dot); dot = fmaf(t0.w, s0.w, dot);              \
      dot = fmaf(t1.x, s1.x, dot); dot = fmaf(t1.y, s1.y, dot);              \
      dot = fmaf(t1.z, s1.z, dot); dot = fmaf(t1.w, s1.w, dot);              \
      dot = fmaf(t2.x, s2.x, dot); dot = fmaf(t2.y, s2.y, dot);              \
      dot = fmaf(t2.z, s2.z, dot); dot = fmaf(t2.w, s2.w, dot);              \
      dot = fmaf(t3.x, s3.x, dot); dot = fmaf(t3.y, s3.y, dot);              \
      dot = fmaf(t3.z, s3.z, dot); dot = fmaf(t3.w, s3.w, dot);              \
      _Pragma("unroll")                                                      \
      for (int off = 32; off > 0; off >>= 1)                                 \
          dot += __shfl_down(dot, off, 64);                                  \
      if (lane == 0) local += fabsf(dot);                                    \
      CFENCE(); /* keep ds_reads above, next GLDS below */                   \
      if (DO_ISSUE) {                                                        \
        _Pragma("unroll")                                                    \
        for (int k = 0; k < 4; ++k)                                          \
            GLDS(trow + ((MI) + 3) * mstride + k * 256,                      \
                 &ring[wave][(MI) % 3][k * 256]);                            \
      }                                                                      \
    } while (0)

    STEP(0, 1, 8);
    STEP(1, 1, 8);
    STEP(2, 1, 8);
    STEP(3, 1, 8);
    STEP(4, 1, 8);
    STEP(5, 0, 8);
    STEP(6, 0, 4);
    STEP(7, 0, 0);
#undef STEP

    if (lane == 0) sbuf[wave] = local;
    __syncthreads();
    if (threadIdx.x == 0)
        partials[blockIdx.x] = sbuf[0] + sbuf[1] + sbuf[2] + sbuf[3];
}

__global__ __launch_bounds__(256) void reduce_partials(
    const float* __restrict__ partials, float* __restrict__ out, int n)
{
    __shared__ float sb[4];
    const int lane = threadIdx.x & 63;
    const int wv   = threadIdx.x >> 6;
    float s = 0.0f;
    for (int i = threadIdx.x; i < n; i += 256) s += partials[i];
#pragma unroll
    for (int off = 32; off > 0; off >>= 1) s += __shfl_down(s, off, 64);
    if (lane == 0) sb[wv] = s;
    __syncthreads();
    if (threadIdx.x == 0) out[0] = sb[0] + sb[1] + sb[2] + sb[3];
}

extern "C" void kernel_launch(void* const* d_in, const int* in_sizes, int n_in,
                              void* d_out, int out_size, void* d_ws, size_t ws_size,
                              hipStream_t stream) {
    const float* src  = (const float*)d_in[0];   // [B, N, D]
    const float* tgts = (const float*)d_in[1];   // [B, M, N, D]
    float* out      = (float*)d_out;             // [1]
    float* partials = (float*)d_ws;              // 2048 floats

    // one wave per (b, n, m-half): B*N*2 waves, 4 waves/block
    const int total_waves = (in_sizes[0] / 1024) * 2;   // 8192
    const int blocks = total_waves / 4;                  // 2048

    orth_loss_main<<<blocks, 256, 0, stream>>>(src, tgts, partials);
    reduce_partials<<<1, 256, 0, stream>>>(partials, out, blocks);
}